// Round 10
// baseline (148.762 us; speedup 1.0000x reference)
//
#include <hip/hip_runtime.h>
#include <hip/hip_bf16.h>

// Problem dims (fixed): B=8, Q=256, K=256, D=256, H=256, DV=512
#define B_  8
#define Q_  256
#define K_  256
#define D_  256
#define H_  256
#define DV_ 512
#define QB  4            // q-rows per attn block

#define SCALE_2LOG2E 2.8853900817779268f   // 2*log2(e): exp(2x) = 2^(x*this)
#define LOG2E_F      1.4426950408889634f

// ---------------------------------------------------------------------------
// Kernel 1: projections + exponentiation (exp factorization):
//   Eq [B][Q][H]  = 2^((queries @ W_q) * 2log2e)
//   EkT[B][H][K]  = 2^((keys    @ W_k)^T * 2log2e)   (transposed)
// Flat 1D grid, b = id&7 (XCD-locality with attn kernel's decode).
// ---------------------------------------------------------------------------
__global__ __launch_bounds__(256) void proj_kernel(
    const float* __restrict__ queries, const float* __restrict__ keys,
    const float* __restrict__ Wq, const float* __restrict__ Wk,
    float* __restrict__ Eq, float* __restrict__ EkT) {
  const int id = blockIdx.x;
  const int b  = id & 7;
  const bool kpath = (id >> 3) & 1;
  const int m0 = ((id >> 4) & 3) * 64;     // q-rows (qpath) or k-cols (kpath)
  const int h0 = ((id >> 6) & 3) * 64;
  const int tid = threadIdx.x;

  __shared__ float As[64][68];             // [d][row]
  __shared__ float Bs[64][68];             // [d][col]

  const int lr = tid >> 4;
  const int lc = (tid & 15) << 2;
  const int r0 = (tid & 15) << 2;
  const int c0 = (tid >> 4) << 2;

  float acc[4][4] = {};

  for (int kk = 0; kk < D_; kk += 64) {
    if (!kpath) {
      #pragma unroll
      for (int i = 0; i < 4; i++) {
        const int row = lr + i * 16;
        float4 va = *(const float4*)&queries[((size_t)(b * Q_ + m0 + row)) * D_ + kk + lc];
        As[lc + 0][row] = va.x; As[lc + 1][row] = va.y;
        As[lc + 2][row] = va.z; As[lc + 3][row] = va.w;
        float4 vb = *(const float4*)&Wq[((size_t)(kk + row)) * H_ + h0 + lc];
        *(float4*)&Bs[row][lc] = vb;
      }
    } else {
      #pragma unroll
      for (int i = 0; i < 4; i++) {
        const int row = lr + i * 16;
        float4 va = *(const float4*)&Wk[((size_t)(kk + row)) * H_ + h0 + lc];
        *(float4*)&As[row][lc] = va;
        float4 vb = *(const float4*)&keys[((size_t)(b * K_ + m0 + row)) * D_ + kk + lc];
        Bs[lc + 0][row] = vb.x; Bs[lc + 1][row] = vb.y;
        Bs[lc + 2][row] = vb.z; Bs[lc + 3][row] = vb.w;
      }
    }
    __syncthreads();

    #pragma unroll 8
    for (int d = 0; d < 64; d++) {
      float4 av = *(const float4*)&As[d][r0];
      float4 bv = *(const float4*)&Bs[d][c0];
      acc[0][0] = fmaf(av.x, bv.x, acc[0][0]); acc[0][1] = fmaf(av.x, bv.y, acc[0][1]);
      acc[0][2] = fmaf(av.x, bv.z, acc[0][2]); acc[0][3] = fmaf(av.x, bv.w, acc[0][3]);
      acc[1][0] = fmaf(av.y, bv.x, acc[1][0]); acc[1][1] = fmaf(av.y, bv.y, acc[1][1]);
      acc[1][2] = fmaf(av.y, bv.z, acc[1][2]); acc[1][3] = fmaf(av.y, bv.w, acc[1][3]);
      acc[2][0] = fmaf(av.z, bv.x, acc[2][0]); acc[2][1] = fmaf(av.z, bv.y, acc[2][1]);
      acc[2][2] = fmaf(av.z, bv.z, acc[2][2]); acc[2][3] = fmaf(av.z, bv.w, acc[2][3]);
      acc[3][0] = fmaf(av.w, bv.x, acc[3][0]); acc[3][1] = fmaf(av.w, bv.y, acc[3][1]);
      acc[3][2] = fmaf(av.w, bv.z, acc[3][2]); acc[3][3] = fmaf(av.w, bv.w, acc[3][3]);
    }
    __syncthreads();
  }

  float* dst = kpath ? EkT : Eq;
  const int ro = kpath ? h0 : m0, co = kpath ? m0 : h0;
  #pragma unroll
  for (int i = 0; i < 4; i++) {
    float4 v;
    v.x = __builtin_amdgcn_exp2f(acc[i][0] * SCALE_2LOG2E);
    v.y = __builtin_amdgcn_exp2f(acc[i][1] * SCALE_2LOG2E);
    v.z = __builtin_amdgcn_exp2f(acc[i][2] * SCALE_2LOG2E);
    v.w = __builtin_amdgcn_exp2f(acc[i][3] * SCALE_2LOG2E);
    *(float4*)&dst[((size_t)(b * 256 + ro + r0 + i)) * 256 + co + c0] = v;
  }
}

// ---------------------------------------------------------------------------
// Kernel 2: fused scores + softmax + PV.
// Round-9 dataflow (each EkT element read ONCE per block; b128 global loads),
// with the three round-9 defects fixed:
//  (1) ALL LDS partial traffic uses contiguous per-wave runs
//      rbuf[slot*1024 + qq*256 + 4*lane]  -> zero bank conflicts.
//  (2) Flat one-shot reduction, 4 barriers total (was 9): 16 waves dump
//      score partials once; waves 0-3 sum 16 slots for their own q-row and
//      do that row's softmax entirely in-wave.
//  (3) VGPR capped at 64 via __launch_bounds__(1024, 8) (32 waves/CU) and
//      no register double-buffer.
// SCORE: wave wid owns h-chunk [16*wid,+16), lane owns k=4*lane..+3, all 4 q
//        in s2v[4] (float4 over k). 4-way h-combined sigmoids (1 rcp / 4 h).
// PV:    wave = (kr = wid>>1: 32 k) x (dvh = wid&1); lane owns 4 dv; attn
//        read as wave-uniform scalar broadcasts; one-shot 8-slot combine by
//        waves 0-1.
// ---------------------------------------------------------------------------
__global__ __launch_bounds__(1024, 8) void attn_kernel(
    const float* __restrict__ Eq, const float* __restrict__ EkT,
    const float* __restrict__ wv, const float* __restrict__ values,
    float* __restrict__ out) {
  const int t    = threadIdx.x;
  const int wid  = t >> 6;
  const int lane = t & 63;
  const int b    = blockIdx.x & 7;          // XCD-locality decode
  const int q0   = (blockIdx.x >> 3) * QB;

  __shared__ float rbuf[16 * 1024];        // 64 KB: score partials / PV partials
  __shared__ float eq_t[QB][H_];           // 4 KB
  __shared__ float wvm2[H_];               // 1 KB (-2*wv)
  __shared__ float attn_q[QB][K_];         // 4 KB  [qq][k]
  __shared__ float psumS[QB];

  // ---- stage eq (4 rows) + wv ----
  if (t < H_) {
    const float* qs = Eq + ((size_t)(b * Q_ + q0)) * H_ + t;
    eq_t[0][t] = qs[0];
    eq_t[1][t] = qs[H_];
    eq_t[2][t] = qs[2 * H_];
    eq_t[3][t] = qs[3 * H_];
    wvm2[t] = -2.0f * wv[t];
  }
  __syncthreads();

  // ---- score: wave's 16-h chunk, 4-way h-combined sigmoids ----
  float4 s2v[QB];
  #pragma unroll
  for (int qq = 0; qq < QB; qq++) s2v[qq] = make_float4(0.f, 0.f, 0.f, 0.f);

  const int hbase = wid * 16;
  const float* ekb = EkT + (size_t)b * H_ * K_ + (size_t)hbase * K_ + 4 * lane;

  for (int st = 0; st < 4; st++) {         // 4 h per step
    float4 ekc[4];
    #pragma unroll
    for (int j = 0; j < 4; j++)
      ekc[j] = *(const float4*)(ekb + (size_t)(st * 4 + j) * K_);
    const int h = hbase + st * 4;
    float4 wvv = *(const float4*)&wvm2[h];
    #pragma unroll
    for (int qq = 0; qq < QB; qq++) {
      float4 eqv = *(const float4*)&eq_t[qq][h];
      float4 s2q = s2v[qq];
      #define SCORE_K(C)                                                      \
      {                                                                       \
        float d0 = fmaf(eqv.x, ekc[0].C, 1.0f);                               \
        float d1 = fmaf(eqv.y, ekc[1].C, 1.0f);                               \
        float d2 = fmaf(eqv.z, ekc[2].C, 1.0f);                               \
        float d3 = fmaf(eqv.w, ekc[3].C, 1.0f);                               \
        float p01 = d0 * d1, p23 = d2 * d3;                                   \
        float n01 = fmaf(wvv.x, d1, wvv.y * d0);                              \
        float n23 = fmaf(wvv.z, d3, wvv.w * d2);                              \
        float num = fmaf(n01, p23, n23 * p01);                                \
        s2q.C = fmaf(num, __builtin_amdgcn_rcpf(p01 * p23), s2q.C);           \
      }
      SCORE_K(x) SCORE_K(y) SCORE_K(z) SCORE_K(w)
      #undef SCORE_K
      s2v[qq] = s2q;
    }
  }

  // ---- dump score partials (contiguous per-wave runs, conflict-free) ----
  #pragma unroll
  for (int qq = 0; qq < QB; qq++)
    *(float4*)&rbuf[wid * 1024 + qq * 256 + 4 * lane] = s2v[qq];
  __syncthreads();

  // ---- combine + softmax: wave qg (< QB) owns row qg; lane holds 4 k ----
  if (wid < QB) {
    const int qg = wid;
    float4 sc = make_float4(0.f, 0.f, 0.f, 0.f);
    #pragma unroll
    for (int s = 0; s < 16; s++) {
      float4 p = *(const float4*)&rbuf[s * 1024 + qg * 256 + 4 * lane];
      sc.x += p.x; sc.y += p.y; sc.z += p.z; sc.w += p.w;
    }
    float m = fmaxf(fmaxf(sc.x, sc.y), fmaxf(sc.z, sc.w));
    #pragma unroll
    for (int mask = 32; mask >= 1; mask >>= 1) m = fmaxf(m, __shfl_xor(m, mask));
    float4 e;
    e.x = __builtin_amdgcn_exp2f((sc.x - m) * LOG2E_F);
    e.y = __builtin_amdgcn_exp2f((sc.y - m) * LOG2E_F);
    e.z = __builtin_amdgcn_exp2f((sc.z - m) * LOG2E_F);
    e.w = __builtin_amdgcn_exp2f((sc.w - m) * LOG2E_F);
    float sl = (e.x + e.y) + (e.z + e.w);
    #pragma unroll
    for (int mask = 32; mask >= 1; mask >>= 1) sl += __shfl_xor(sl, mask);
    if (lane == 0) psumS[qg] = sl;
    *(float4*)&attn_q[qg][4 * lane] = e;   // contiguous b128, conflict-free
  }
  __syncthreads();

  // ---- PV: wave = (kr owns 32 k) x (dvh half); lane owns 4 dv ----
  const int kr  = wid >> 1;
  const int dvh = wid & 1;
  const float* vbase = values + (size_t)b * K_ * DV_ + dvh * 256 + 4 * lane;
  float4 pacc[QB];
  #pragma unroll
  for (int qq = 0; qq < QB; qq++) pacc[qq] = make_float4(0.f, 0.f, 0.f, 0.f);
  #pragma unroll 4
  for (int kk = 0; kk < 32; kk++) {
    const int k = kr * 32 + kk;
    float4 v = *(const float4*)(vbase + (size_t)k * DV_);
    float a0 = attn_q[0][k];   // wave-uniform broadcast reads
    float a1 = attn_q[1][k];
    float a2 = attn_q[2][k];
    float a3 = attn_q[3][k];
    pacc[0].x = fmaf(a0, v.x, pacc[0].x); pacc[0].y = fmaf(a0, v.y, pacc[0].y);
    pacc[0].z = fmaf(a0, v.z, pacc[0].z); pacc[0].w = fmaf(a0, v.w, pacc[0].w);
    pacc[1].x = fmaf(a1, v.x, pacc[1].x); pacc[1].y = fmaf(a1, v.y, pacc[1].y);
    pacc[1].z = fmaf(a1, v.z, pacc[1].z); pacc[1].w = fmaf(a1, v.w, pacc[1].w);
    pacc[2].x = fmaf(a2, v.x, pacc[2].x); pacc[2].y = fmaf(a2, v.y, pacc[2].y);
    pacc[2].z = fmaf(a2, v.z, pacc[2].z); pacc[2].w = fmaf(a2, v.w, pacc[2].w);
    pacc[3].x = fmaf(a3, v.x, pacc[3].x); pacc[3].y = fmaf(a3, v.y, pacc[3].y);
    pacc[3].z = fmaf(a3, v.z, pacc[3].z); pacc[3].w = fmaf(a3, v.w, pacc[3].w);
  }
  #pragma unroll
  for (int qq = 0; qq < QB; qq++)
    *(float4*)&rbuf[wid * 1024 + qq * 256 + 4 * lane] = pacc[qq];
  __syncthreads();

  // ---- one-shot 8-slot combine + output by waves 0 (dvh=0) and 1 (dvh=1) ----
  if (wid < 2) {
    float4 oacc[QB];
    #pragma unroll
    for (int qq = 0; qq < QB; qq++) oacc[qq] = make_float4(0.f, 0.f, 0.f, 0.f);
    #pragma unroll
    for (int p = 0; p < 8; p++) {
      const float* r = &rbuf[(2 * p + wid) * 1024];
      #pragma unroll
      for (int qq = 0; qq < QB; qq++) {
        float4 pp = *(const float4*)&r[qq * 256 + 4 * lane];
        oacc[qq].x += pp.x; oacc[qq].y += pp.y;
        oacc[qq].z += pp.z; oacc[qq].w += pp.w;
      }
    }
    #pragma unroll
    for (int qq = 0; qq < QB; qq++) {
      float rs = __builtin_amdgcn_rcpf(psumS[qq]);
      float4 o = make_float4(oacc[qq].x * rs, oacc[qq].y * rs,
                             oacc[qq].z * rs, oacc[qq].w * rs);
      *(float4*)&out[((size_t)(b * Q_ + q0 + qq)) * DV_ + wid * 256 + 4 * lane] = o;
    }
  }
}

extern "C" void kernel_launch(void* const* d_in, const int* in_sizes, int n_in,
                              void* d_out, int out_size, void* d_ws, size_t ws_size,
                              hipStream_t stream) {
  const float* queries = (const float*)d_in[0];  // [8,256,256]
  const float* keys    = (const float*)d_in[1];  // [8,256,256]
  const float* values  = (const float*)d_in[2];  // [8,256,512]
  const float* W_q     = (const float*)d_in[3];  // [256,256]
  const float* W_k     = (const float*)d_in[4];  // [256,256]
  const float* w_v     = (const float*)d_in[5];  // [256]
  float* out = (float*)d_out;

  float* Eq  = (float*)d_ws;                     // [8][256][256] = 2 MB
  float* EkT = Eq + (size_t)B_ * Q_ * H_;        // [8][256][256] = 2 MB

  dim3 pgrid(256), pblk(256);
  proj_kernel<<<pgrid, pblk, 0, stream>>>(queries, keys, W_q, W_k, Eq, EkT);

  dim3 agrid(Q_ / QB * B_), ablk(1024);
  attn_kernel<<<agrid, ablk, 0, stream>>>(Eq, EkT, w_v, values, out);
}

// Round 11
// 43.599 us; speedup vs baseline: 3.4121x; 3.4121x over previous
//
#include <hip/hip_runtime.h>
#include <hip/hip_bf16.h>

// Problem dims (fixed): B=8, Q=256, K=256, D=256, H=256, DV=512
#define B_  8
#define Q_  256
#define K_  256
#define D_  256
#define H_  256
#define DV_ 512
#define QB  4            // q-rows per attn block

#define SCALE_2LOG2E 2.8853900817779268f   // 2*log2(e): exp(2x) = 2^(x*this)
#define LOG2E_F      1.4426950408889634f

// ---------------------------------------------------------------------------
// Kernel 1: projections + exponentiation (exp factorization):
//   Eq [B][Q][H]  = 2^((queries @ W_q) * 2log2e)
//   EkT[B][H][K]  = 2^((keys    @ W_k)^T * 2log2e)   (transposed)
// Flat 1D grid, b = id&7 (XCD-locality with attn kernel's decode).
// ---------------------------------------------------------------------------
__global__ __launch_bounds__(256) void proj_kernel(
    const float* __restrict__ queries, const float* __restrict__ keys,
    const float* __restrict__ Wq, const float* __restrict__ Wk,
    float* __restrict__ Eq, float* __restrict__ EkT) {
  const int id = blockIdx.x;
  const int b  = id & 7;
  const bool kpath = (id >> 3) & 1;
  const int m0 = ((id >> 4) & 3) * 64;     // q-rows (qpath) or k-cols (kpath)
  const int h0 = ((id >> 6) & 3) * 64;
  const int tid = threadIdx.x;

  __shared__ float As[64][68];             // [d][row]
  __shared__ float Bs[64][68];             // [d][col]

  const int lr = tid >> 4;
  const int lc = (tid & 15) << 2;
  const int r0 = (tid & 15) << 2;
  const int c0 = (tid >> 4) << 2;

  float acc[4][4] = {};

  for (int kk = 0; kk < D_; kk += 64) {
    if (!kpath) {
      #pragma unroll
      for (int i = 0; i < 4; i++) {
        const int row = lr + i * 16;
        float4 va = *(const float4*)&queries[((size_t)(b * Q_ + m0 + row)) * D_ + kk + lc];
        As[lc + 0][row] = va.x; As[lc + 1][row] = va.y;
        As[lc + 2][row] = va.z; As[lc + 3][row] = va.w;
        float4 vb = *(const float4*)&Wq[((size_t)(kk + row)) * H_ + h0 + lc];
        *(float4*)&Bs[row][lc] = vb;
      }
    } else {
      #pragma unroll
      for (int i = 0; i < 4; i++) {
        const int row = lr + i * 16;
        float4 va = *(const float4*)&Wk[((size_t)(kk + row)) * H_ + h0 + lc];
        *(float4*)&As[row][lc] = va;
        float4 vb = *(const float4*)&keys[((size_t)(b * K_ + m0 + row)) * D_ + kk + lc];
        Bs[lc + 0][row] = vb.x; Bs[lc + 1][row] = vb.y;
        Bs[lc + 2][row] = vb.z; Bs[lc + 3][row] = vb.w;
      }
    }
    __syncthreads();

    #pragma unroll 8
    for (int d = 0; d < 64; d++) {
      float4 av = *(const float4*)&As[d][r0];
      float4 bv = *(const float4*)&Bs[d][c0];
      acc[0][0] = fmaf(av.x, bv.x, acc[0][0]); acc[0][1] = fmaf(av.x, bv.y, acc[0][1]);
      acc[0][2] = fmaf(av.x, bv.z, acc[0][2]); acc[0][3] = fmaf(av.x, bv.w, acc[0][3]);
      acc[1][0] = fmaf(av.y, bv.x, acc[1][0]); acc[1][1] = fmaf(av.y, bv.y, acc[1][1]);
      acc[1][2] = fmaf(av.y, bv.z, acc[1][2]); acc[1][3] = fmaf(av.y, bv.w, acc[1][3]);
      acc[2][0] = fmaf(av.z, bv.x, acc[2][0]); acc[2][1] = fmaf(av.z, bv.y, acc[2][1]);
      acc[2][2] = fmaf(av.z, bv.z, acc[2][2]); acc[2][3] = fmaf(av.z, bv.w, acc[2][3]);
      acc[3][0] = fmaf(av.w, bv.x, acc[3][0]); acc[3][1] = fmaf(av.w, bv.y, acc[3][1]);
      acc[3][2] = fmaf(av.w, bv.z, acc[3][2]); acc[3][3] = fmaf(av.w, bv.w, acc[3][3]);
    }
    __syncthreads();
  }

  float* dst = kpath ? EkT : Eq;
  const int ro = kpath ? h0 : m0, co = kpath ? m0 : h0;
  #pragma unroll
  for (int i = 0; i < 4; i++) {
    float4 v;
    v.x = __builtin_amdgcn_exp2f(acc[i][0] * SCALE_2LOG2E);
    v.y = __builtin_amdgcn_exp2f(acc[i][1] * SCALE_2LOG2E);
    v.z = __builtin_amdgcn_exp2f(acc[i][2] * SCALE_2LOG2E);
    v.w = __builtin_amdgcn_exp2f(acc[i][3] * SCALE_2LOG2E);
    *(float4*)&dst[((size_t)(b * 256 + ro + r0 + i)) * 256 + co + c0] = v;
  }
}

// ---------------------------------------------------------------------------
// Kernel 2: fused scores + softmax + PV.
// Round-10 body (conflict-free LDS runs, 4 barriers, once-per-block EkT reads)
// with the spill-inducing __launch_bounds__(1024, 8) REVERTED to plain
// __launch_bounds__(1024): r10 showed (1024,8) forces VGPR=32 -> 220+ MB of
// scratch spill traffic. Plain bound gave VGPR=64 in r9 with a fatter body.
// SCORE: wave wid owns h-chunk [16*wid,+16), lane owns k=4*lane..+3, all 4 q
//        in s2v[4] (float4 over k). 4-way h-combined sigmoids (1 rcp / 4 h).
// REDUCE: one-shot dump; waves 0-3 each sum 16 slots for their q-row and do
//        that row's softmax in-wave.
// PV:    wave = (kr = wid>>1: 32 k) x (dvh = wid&1); lane owns 4 dv; attn
//        read as wave-uniform scalar broadcasts; one-shot 8-slot combine by
//        waves 0-1.
// ---------------------------------------------------------------------------
__global__ __launch_bounds__(1024) void attn_kernel(
    const float* __restrict__ Eq, const float* __restrict__ EkT,
    const float* __restrict__ wv, const float* __restrict__ values,
    float* __restrict__ out) {
  const int t    = threadIdx.x;
  const int wid  = t >> 6;
  const int lane = t & 63;
  const int b    = blockIdx.x & 7;          // XCD-locality decode
  const int q0   = (blockIdx.x >> 3) * QB;

  __shared__ float rbuf[16 * 1024];        // 64 KB: score partials / PV partials
  __shared__ float eq_t[QB][H_];           // 4 KB
  __shared__ float wvm2[H_];               // 1 KB (-2*wv)
  __shared__ float attn_q[QB][K_];         // 4 KB  [qq][k]
  __shared__ float psumS[QB];

  // ---- stage eq (4 rows) + wv ----
  if (t < H_) {
    const float* qs = Eq + ((size_t)(b * Q_ + q0)) * H_ + t;
    eq_t[0][t] = qs[0];
    eq_t[1][t] = qs[H_];
    eq_t[2][t] = qs[2 * H_];
    eq_t[3][t] = qs[3 * H_];
    wvm2[t] = -2.0f * wv[t];
  }
  __syncthreads();

  // ---- score: wave's 16-h chunk, 4-way h-combined sigmoids ----
  float4 s2v[QB];
  #pragma unroll
  for (int qq = 0; qq < QB; qq++) s2v[qq] = make_float4(0.f, 0.f, 0.f, 0.f);

  const int hbase = wid * 16;
  const float* ekb = EkT + (size_t)b * H_ * K_ + (size_t)hbase * K_ + 4 * lane;

  for (int st = 0; st < 4; st++) {         // 4 h per step
    float4 ekc[4];
    #pragma unroll
    for (int j = 0; j < 4; j++)
      ekc[j] = *(const float4*)(ekb + (size_t)(st * 4 + j) * K_);
    const int h = hbase + st * 4;
    float4 wvv = *(const float4*)&wvm2[h];
    #pragma unroll
    for (int qq = 0; qq < QB; qq++) {
      float4 eqv = *(const float4*)&eq_t[qq][h];
      float4 s2q = s2v[qq];
      #define SCORE_K(C)                                                      \
      {                                                                       \
        float d0 = fmaf(eqv.x, ekc[0].C, 1.0f);                               \
        float d1 = fmaf(eqv.y, ekc[1].C, 1.0f);                               \
        float d2 = fmaf(eqv.z, ekc[2].C, 1.0f);                               \
        float d3 = fmaf(eqv.w, ekc[3].C, 1.0f);                               \
        float p01 = d0 * d1, p23 = d2 * d3;                                   \
        float n01 = fmaf(wvv.x, d1, wvv.y * d0);                              \
        float n23 = fmaf(wvv.z, d3, wvv.w * d2);                              \
        float num = fmaf(n01, p23, n23 * p01);                                \
        s2q.C = fmaf(num, __builtin_amdgcn_rcpf(p01 * p23), s2q.C);           \
      }
      SCORE_K(x) SCORE_K(y) SCORE_K(z) SCORE_K(w)
      #undef SCORE_K
      s2v[qq] = s2q;
    }
  }

  // ---- dump score partials (contiguous per-wave runs, conflict-free) ----
  #pragma unroll
  for (int qq = 0; qq < QB; qq++)
    *(float4*)&rbuf[wid * 1024 + qq * 256 + 4 * lane] = s2v[qq];
  __syncthreads();

  // ---- combine + softmax: wave qg (< QB) owns row qg; lane holds 4 k ----
  if (wid < QB) {
    const int qg = wid;
    float4 sc = make_float4(0.f, 0.f, 0.f, 0.f);
    #pragma unroll
    for (int s = 0; s < 16; s++) {
      float4 p = *(const float4*)&rbuf[s * 1024 + qg * 256 + 4 * lane];
      sc.x += p.x; sc.y += p.y; sc.z += p.z; sc.w += p.w;
    }
    float m = fmaxf(fmaxf(sc.x, sc.y), fmaxf(sc.z, sc.w));
    #pragma unroll
    for (int mask = 32; mask >= 1; mask >>= 1) m = fmaxf(m, __shfl_xor(m, mask));
    float4 e;
    e.x = __builtin_amdgcn_exp2f((sc.x - m) * LOG2E_F);
    e.y = __builtin_amdgcn_exp2f((sc.y - m) * LOG2E_F);
    e.z = __builtin_amdgcn_exp2f((sc.z - m) * LOG2E_F);
    e.w = __builtin_amdgcn_exp2f((sc.w - m) * LOG2E_F);
    float sl = (e.x + e.y) + (e.z + e.w);
    #pragma unroll
    for (int mask = 32; mask >= 1; mask >>= 1) sl += __shfl_xor(sl, mask);
    if (lane == 0) psumS[qg] = sl;
    *(float4*)&attn_q[qg][4 * lane] = e;   // contiguous b128, conflict-free
  }
  __syncthreads();

  // ---- PV: wave = (kr owns 32 k) x (dvh half); lane owns 4 dv ----
  const int kr  = wid >> 1;
  const int dvh = wid & 1;
  const float* vbase = values + (size_t)b * K_ * DV_ + dvh * 256 + 4 * lane;
  float4 pacc[QB];
  #pragma unroll
  for (int qq = 0; qq < QB; qq++) pacc[qq] = make_float4(0.f, 0.f, 0.f, 0.f);
  #pragma unroll 4
  for (int kk = 0; kk < 32; kk++) {
    const int k = kr * 32 + kk;
    float4 v = *(const float4*)(vbase + (size_t)k * DV_);
    float a0 = attn_q[0][k];   // wave-uniform broadcast reads
    float a1 = attn_q[1][k];
    float a2 = attn_q[2][k];
    float a3 = attn_q[3][k];
    pacc[0].x = fmaf(a0, v.x, pacc[0].x); pacc[0].y = fmaf(a0, v.y, pacc[0].y);
    pacc[0].z = fmaf(a0, v.z, pacc[0].z); pacc[0].w = fmaf(a0, v.w, pacc[0].w);
    pacc[1].x = fmaf(a1, v.x, pacc[1].x); pacc[1].y = fmaf(a1, v.y, pacc[1].y);
    pacc[1].z = fmaf(a1, v.z, pacc[1].z); pacc[1].w = fmaf(a1, v.w, pacc[1].w);
    pacc[2].x = fmaf(a2, v.x, pacc[2].x); pacc[2].y = fmaf(a2, v.y, pacc[2].y);
    pacc[2].z = fmaf(a2, v.z, pacc[2].z); pacc[2].w = fmaf(a2, v.w, pacc[2].w);
    pacc[3].x = fmaf(a3, v.x, pacc[3].x); pacc[3].y = fmaf(a3, v.y, pacc[3].y);
    pacc[3].z = fmaf(a3, v.z, pacc[3].z); pacc[3].w = fmaf(a3, v.w, pacc[3].w);
  }
  #pragma unroll
  for (int qq = 0; qq < QB; qq++)
    *(float4*)&rbuf[wid * 1024 + qq * 256 + 4 * lane] = pacc[qq];
  __syncthreads();

  // ---- one-shot 8-slot combine + output by waves 0 (dvh=0) and 1 (dvh=1) ----
  if (wid < 2) {
    float4 oacc[QB];
    #pragma unroll
    for (int qq = 0; qq < QB; qq++) oacc[qq] = make_float4(0.f, 0.f, 0.f, 0.f);
    #pragma unroll
    for (int p = 0; p < 8; p++) {
      const float* r = &rbuf[(2 * p + wid) * 1024];
      #pragma unroll
      for (int qq = 0; qq < QB; qq++) {
        float4 pp = *(const float4*)&r[qq * 256 + 4 * lane];
        oacc[qq].x += pp.x; oacc[qq].y += pp.y;
        oacc[qq].z += pp.z; oacc[qq].w += pp.w;
      }
    }
    #pragma unroll
    for (int qq = 0; qq < QB; qq++) {
      float rs = __builtin_amdgcn_rcpf(psumS[qq]);
      float4 o = make_float4(oacc[qq].x * rs, oacc[qq].y * rs,
                             oacc[qq].z * rs, oacc[qq].w * rs);
      *(float4*)&out[((size_t)(b * Q_ + q0 + qq)) * DV_ + wid * 256 + 4 * lane] = o;
    }
  }
}

extern "C" void kernel_launch(void* const* d_in, const int* in_sizes, int n_in,
                              void* d_out, int out_size, void* d_ws, size_t ws_size,
                              hipStream_t stream) {
  const float* queries = (const float*)d_in[0];  // [8,256,256]
  const float* keys    = (const float*)d_in[1];  // [8,256,256]
  const float* values  = (const float*)d_in[2];  // [8,256,512]
  const float* W_q     = (const float*)d_in[3];  // [256,256]
  const float* W_k     = (const float*)d_in[4];  // [256,256]
  const float* w_v     = (const float*)d_in[5];  // [256]
  float* out = (float*)d_out;

  float* Eq  = (float*)d_ws;                     // [8][256][256] = 2 MB
  float* EkT = Eq + (size_t)B_ * Q_ * H_;        // [8][256][256] = 2 MB

  dim3 pgrid(256), pblk(256);
  proj_kernel<<<pgrid, pblk, 0, stream>>>(queries, keys, W_q, W_k, Eq, EkT);

  dim3 agrid(Q_ / QB * B_), ablk(1024);
  attn_kernel<<<agrid, ablk, 0, stream>>>(Eq, EkT, w_v, values, out);
}